// Round 5
// baseline (185.966 us; speedup 1.0000x reference)
//
#include <hip/hip_runtime.h>

// LocalConnectivity: diamond (L1-ball radius 5) circular convolution over
// (B=64, H=512, W=512) fp32, weight per L1-distance d: w_d = d_in[1][d-1].
//
// Decomposition (exact):
//   h_a[r][j] = sum_{|b| <= 5-a} w_{a+|b|} * s[r][(j+b)&511]   (h_0 excludes b=0)
//   out[i][j] = h_0[i][j] + sum_{a=1..5} (h_a[i-a][j] + h_a[i+a][j])
//
// R1: forced 64-VGPR cap on 124-reg kernel -> spills -> 217 us.
// R2: direct global reads: 67 us, latency-bound.
// R3: LDS 6-slot ring, 128thr x 4col, per-iter barriers: 43.4 us.
// R4 FAILED: forced __launch_bounds__(256,8) -> spills, 157 us. Never force.
// R5: 512thr x 1col: 49 us, LDS-issue-bound (scalar b32 reads).
// R6: 256thr x 2col, b64 reads, counted vmcnt + per-iter barrier: 54 us.
//     Residency stuck ~2.3 blocks/CU in R3/R5/R6: barrier lockstep exposes
//     one HBM latency per iteration.
// R7: whole-strip staging, ONE barrier: ~38 us (inferred; fell below the
//     42us harness fills). Blocks co-scheduled -> stage phases and compute
//     phases still alternate in lockstep across the CU; zero overlap.
// R8 (this): ZERO barriers. Each wave autonomous: owns a 128-col x 32-row
//     tile (64 lanes x 2 cols), streams 42 source rows through a wave-
//     private 8-slot LDS ring (8 KB/wave, 32 KB/block). Staging = ONE
//     global_load_lds size=16 per row (lane*16B = 256-col window incl.
//     +-6 halo; per-lane global addr handles circular col wrap; granules
//     never straddle the wrap since offsets are x4 floats). Pipeline depth
//     6 rows; per-iter s_waitcnt vmcnt(min(6,41-rr)) (compile-time literal)
//     drains exactly row rr. A wave reads only LDS it staged itself ->
//     vmcnt alone gives visibility; no __syncthreads anywhere. 1024 blocks
//     = 4 blocks/CU, all resident. Vertical redundancy 42/32 = 1.31x (was
//     1.625x). b64 halo reads: 64 lanes x 8B = 512B = LDS BW floor, no
//     true conflicts (stride-2-word pattern covers all 32 banks uniformly).

#define LC_H 512
#define LC_W 512
#define LC_CHUNK 32                 // output rows per wave
#define LC_NT 256                   // 4 waves/block
#define LC_NITER (LC_CHUNK + 10)    // 42 source rows per wave
#define LC_SLOTS 8                  // LDS ring slots (power of 2)
#define LC_SW 256                   // staged cols per row (incl. halo)

typedef const __attribute__((address_space(1))) void* lc_gvp;
typedef __attribute__((address_space(3))) void* lc_lvp;

__global__ __launch_bounds__(LC_NT)
void LocalConnectivity_kernel(const float* __restrict__ in,
                              const float* __restrict__ wp,
                              float* __restrict__ out) {
    const int t = threadIdx.x;
    const int w = t >> 6;             // wave id 0..3 -> column stripe
    const int l = t & 63;             // lane
    const int b = blockIdx.y;         // batch
    const int rbase = blockIdx.x * LC_CHUNK;   // first output row

    const float w1 = wp[0], w2 = wp[1], w3 = wp[2], w4 = wp[3], w5 = wp[4];

    const float* __restrict__ src = in + (size_t)b * (LC_H * LC_W);
    float* __restrict__ dst = out + (size_t)b * (LC_H * LC_W);

    // 4 waves x 8 slots x 256 cols = 32 KB; each wave touches only its 8 KB.
    __shared__ __attribute__((aligned(16))) float lds[4 * LC_SLOTS * LC_SW];
    float* __restrict__ wlds = &lds[w * (LC_SLOTS * LC_SW)];

    // loop-invariant lane addressing
    // staged window of this wave: global cols [128w-64, 128w+192) mod 512;
    // lane l stages 4 floats starting at:
    const int gcol = (128 * w - 64 + 4 * l) & (LC_W - 1);
    // local col of v[0] (= global col 128w+2l-6) in the 256-col window:
    const int lofs = 58 + 2 * l;
    const int ocol = 128 * w + 2 * l;  // first of this lane's 2 output cols

    // DMA source row j (grid row (rbase+j-5)&511) -> ring slot j&7.
    // LDS dest = wave-uniform base + lane*16 (linear), matches layout.
#define LC_ISSUE(j) do {                                                      \
        const int grow_ = (rbase + (j) - 5) & (LC_H - 1);                     \
        __builtin_amdgcn_global_load_lds(                                     \
            (lc_gvp)(src + (size_t)grow_ * LC_W + gcol),                      \
            (lc_lvp)(wlds + ((j) & (LC_SLOTS - 1)) * LC_SW + 4 * l),          \
            16, 0, 0);                                                        \
    } while (0)

    float acc[11][2];
#pragma unroll
    for (int k = 0; k < 11; ++k) { acc[k][0] = 0.f; acc[k][1] = 0.f; }

    // prologue: rows 0..5 in flight (6 outstanding DMAs)
#pragma unroll
    for (int j = 0; j < 6; ++j) LC_ISSUE(j);

#pragma unroll
    for (int rr = 0; rr < LC_NITER; ++rr) {
        // keep the pipeline 6 rows deep
        if (rr + 6 < LC_NITER) LC_ISSUE(rr + 6);

        // drain exactly row rr (allow rows rr+1..rr+6 to stay in flight).
        // rr is compile-time under full unroll -> literal folds.
        {
            const int nout = (LC_NITER - 1 - rr < 6) ? (LC_NITER - 1 - rr) : 6;
            if (nout == 6)      asm volatile("s_waitcnt vmcnt(6)" ::: "memory");
            else if (nout == 5) asm volatile("s_waitcnt vmcnt(5)" ::: "memory");
            else if (nout == 4) asm volatile("s_waitcnt vmcnt(4)" ::: "memory");
            else if (nout == 3) asm volatile("s_waitcnt vmcnt(3)" ::: "memory");
            else if (nout == 2) asm volatile("s_waitcnt vmcnt(2)" ::: "memory");
            else if (nout == 1) asm volatile("s_waitcnt vmcnt(1)" ::: "memory");
            else                asm volatile("s_waitcnt vmcnt(0)" ::: "memory");
        }

        // halo cols (local lofs..lofs+13) of source row rr: 7 x ds_read_b64.
        // 64 lanes x 8B stride-2-word = 128 consecutive words = uniform over
        // all 32 banks (BW floor, no conflicts).
        const float* slotp = wlds + (rr & (LC_SLOTS - 1)) * LC_SW;
        float v[14];
#pragma unroll
        for (int o = 0; o < 7; ++o) {
            const float2 f =
                *reinterpret_cast<const float2*>(slotp + lofs + 2 * o);
            v[o * 2 + 0] = f.x;
            v[o * 2 + 1] = f.y;
        }

        // horizontal pass + vertical scatter fused: v[6+q] is my column q
        // (global ocol+q). r_off compile-time per unrolled iter -> guards and
        // %11 ring indices fold; acc stays in named registers.
        const int r_off = rr - 5;
#pragma unroll
        for (int q = 0; q < 2; ++q) {
            const float p0 = v[6 + q];
            const float p1 = v[5 + q] + v[7 + q];
            const float p2 = v[4 + q] + v[8 + q];
            const float p3 = v[3 + q] + v[9 + q];
            const float p4 = v[2 + q] + v[10 + q];
            const float p5 = v[1 + q] + v[11 + q];

            float hv;
            hv = w1 * p1 + w2 * p2 + w3 * p3 + w4 * p4 + w5 * p5;
            if (r_off >= 0 && r_off < LC_CHUNK) acc[r_off % 11][q] += hv;
            hv = w1 * p0 + w2 * p1 + w3 * p2 + w4 * p3 + w5 * p4;
            {
                const int op = r_off + 1, om = r_off - 1;
                if (op >= 0 && op < LC_CHUNK) acc[op % 11][q] += hv;
                if (om >= 0 && om < LC_CHUNK) acc[om % 11][q] += hv;
            }
            hv = w2 * p0 + w3 * p1 + w4 * p2 + w5 * p3;
            {
                const int op = r_off + 2, om = r_off - 2;
                if (op >= 0 && op < LC_CHUNK) acc[op % 11][q] += hv;
                if (om >= 0 && om < LC_CHUNK) acc[om % 11][q] += hv;
            }
            hv = w3 * p0 + w4 * p1 + w5 * p2;
            {
                const int op = r_off + 3, om = r_off - 3;
                if (op >= 0 && op < LC_CHUNK) acc[op % 11][q] += hv;
                if (om >= 0 && om < LC_CHUNK) acc[om % 11][q] += hv;
            }
            hv = w4 * p0 + w5 * p1;
            {
                const int op = r_off + 4, om = r_off - 4;
                if (op >= 0 && op < LC_CHUNK) acc[op % 11][q] += hv;
                if (om >= 0 && om < LC_CHUNK) acc[om % 11][q] += hv;
            }
            hv = w5 * p0;
            {
                const int op = r_off + 5, om = r_off - 5;
                if (op >= 0 && op < LC_CHUNK) acc[op % 11][q] += hv;
                if (om >= 0 && om < LC_CHUNK) acc[om % 11][q] += hv;
            }
        }

        // output row oc = rr - 10 complete after this source row
        const int oc = rr - 10;
        if (oc >= 0 && oc < LC_CHUNK) {
            const int slot = oc % 11;
            float2 f;
            f.x = acc[slot][0];
            f.y = acc[slot][1];
            *reinterpret_cast<float2*>(
                dst + (size_t)(rbase + oc) * LC_W + ocol) = f;
            acc[slot][0] = 0.f;
            acc[slot][1] = 0.f;
        }
    }
#undef LC_ISSUE
}

extern "C" void kernel_launch(void* const* d_in, const int* in_sizes, int n_in,
                              void* d_out, int out_size, void* d_ws, size_t ws_size,
                              hipStream_t stream) {
    const float* grid_spikes = (const float*)d_in[0];       // 64*512*512 fp32
    const float* distance_weights = (const float*)d_in[1];  // 5 fp32
    float* out = (float*)d_out;

    dim3 grid(LC_H / LC_CHUNK, 64);  // 16 row-chunks x 64 batches = 1024 blocks
    dim3 block(LC_NT);
    LocalConnectivity_kernel<<<grid, block, 0, stream>>>(grid_spikes, distance_weights, out);
}

// Round 6
// 120.100 us; speedup vs baseline: 1.5484x; 1.5484x over previous
//
#include <hip/hip_runtime.h>

// LocalConnectivity: diamond (L1-ball radius 5) circular convolution over
// (B=64, H=512, W=512) fp32, weight per L1-distance d: w_d = d_in[1][d-1].
//
// Decomposition (exact):
//   h_a[r][j] = sum_{|b| <= 5-a} w_{a+|b|} * s[r][(j+b)&511]   (h_0 excludes b=0)
//   out[i][j] = h_0[i][j] + sum_{a=1..5} (h_a[i-a][j] + h_a[i+a][j])
//
// Ledger: R1 forced-cap spills 217us | R2 direct-global 67us latency-bound |
//   R3 6-slot ring + per-iter barrier 43us | R4 forced launch_bounds spills
//   157us (never force) | R5 512thr scalar-LDS-reads 49us LDS-issue-bound |
//   R6 per-iter counted vmcnt 54us (prefetch depth 2 << latency) |
//   R7 whole-strip stage + ONE vmcnt(0) barrier: ~38-43us. Stage and compute
//   are serial phases (all-block lockstep); zero-overlap arithmetic matches. |
//   R8 wave-autonomous per-row DMA ring: 110us. Fine-grained DMA (1 issue/row,
//   per-lane wrapped addrs, M0 setup) starves the memory pipe; 6-row cover
//   << latency. Bulk staging + few barriers is the proven shape.
// R9 (this): R7 with the single barrier split into FOUR chunk barriers with
//   counted vmcnt (T3/T4 at block scale). Issue all 52 row-DMAs upfront
//   (in row order -> vmcnt drains oldest-first = row order, m135), then:
//   wait vmcnt(38) -> barrier -> compute rows 0..6   (38 = 2*(26-7) younger)
//   wait vmcnt(26) -> barrier -> compute rows 7..12
//   wait vmcnt(12) -> barrier -> compute rows 13..19
//   wait vmcnt(0)  -> barrier -> compute rows 20..25
//   Startup = first-arrival of 14 loads (not 52); each later chunk covered by
//   ~1k cyc of preceding compute. Compute body byte-identical to R7/R6.
//   LDS 52KB -> 3 blocks/CU; VGPR ~52 (no forcing).

#define LC_H 512
#define LC_W 512
#define LC_TY 16
#define LC_NT 256   // threads per block; each owns 2 columns
#define LC_NR (LC_TY + 10)  // 26 source rows per strip

typedef const __attribute__((address_space(1))) void* lc_gvp;
typedef __attribute__((address_space(3))) void* lc_lvp;

__global__ __launch_bounds__(LC_NT)
void LocalConnectivity_kernel(const float* __restrict__ in,
                              const float* __restrict__ wp,
                              float* __restrict__ out) {
    const int t = threadIdx.x;            // column-pair index 0..255
    const int b = blockIdx.y;             // batch
    const int r0 = blockIdx.x * LC_TY;    // first output row of strip

    const float w1 = wp[0], w2 = wp[1], w3 = wp[2], w4 = wp[3], w5 = wp[4];

    const float* __restrict__ src = in + (size_t)b * (LC_H * LC_W);
    float* __restrict__ dst = out + (size_t)b * (LC_H * LC_W);

    __shared__ __attribute__((aligned(16))) float lds[LC_NR * LC_W]; // 52 KB

    // ---- stage the full strip: source row j -> LDS row j, 2 DMA insts each,
    // issued back-to-back in ROW ORDER (vmcnt completion accounting is
    // oldest-first in issue order -> counted waits below are exact).
#pragma unroll
    for (int j = 0; j < LC_NR; ++j) {
        const float* rp = src + ((r0 + j - 5) & (LC_H - 1)) * LC_W;
        float* lp = &lds[j * LC_W];
        __builtin_amdgcn_global_load_lds((lc_gvp)(rp + t),
                                         (lc_lvp)(lp + t), 4, 0, 0);
        __builtin_amdgcn_global_load_lds((lc_gvp)(rp + LC_NT + t),
                                         (lc_lvp)(lp + LC_NT + t), 4, 0, 0);
    }

    float acc[11][2];
#pragma unroll
    for (int k = 0; k < 11; ++k) { acc[k][0] = 0.f; acc[k][1] = 0.f; }

    // counted wait + barrier: rows 0..R landed when <= 2*(26-(R+1)) younger
    // loads remain outstanding. Memory-clobber asm pins LDS reads below.
#define LC_WAITB(n) do {                                                     \
        asm volatile("s_waitcnt vmcnt(" #n ")" ::: "memory");                \
        __builtin_amdgcn_s_barrier();                                        \
        asm volatile("" ::: "memory");                                       \
    } while (0)

#pragma unroll
    for (int rr = 0; rr < LC_NR; ++rr) {
        // chunk boundaries: rows {0..6 | 7..12 | 13..19 | 20..25}
        if (rr == 0)       LC_WAITB(38);
        else if (rr == 7)  LC_WAITB(26);
        else if (rr == 13) LC_WAITB(12);
        else if (rr == 20) LC_WAITB(0);

        // halo cols 2t-6 .. 2t+7 of source row rr: 7 x ds_read_b64
        const float* slotp = &lds[rr * LC_W];
        float v[14];
#pragma unroll
        for (int o = 0; o < 7; ++o) {
            const int cb = (t + o - 3) & (LC_NT - 1);
            const float2 f = *reinterpret_cast<const float2*>(slotp + cb * 2);
            v[o * 2 + 0] = f.x;
            v[o * 2 + 1] = f.y;
        }

        // horizontal pass + vertical scatter fused: v[6+q] is my column q
        // (global 2t+q). r_off is compile-time per unrolled iter -> guards
        // and %11 ring indices fold; acc stays in named registers.
        const int r_off = rr - 5;
#pragma unroll
        for (int q = 0; q < 2; ++q) {
            const float p0 = v[6 + q];
            const float p1 = v[5 + q] + v[7 + q];
            const float p2 = v[4 + q] + v[8 + q];
            const float p3 = v[3 + q] + v[9 + q];
            const float p4 = v[2 + q] + v[10 + q];
            const float p5 = v[1 + q] + v[11 + q];

            float hv;
            hv = w1 * p1 + w2 * p2 + w3 * p3 + w4 * p4 + w5 * p5;
            if (r_off >= 0 && r_off < LC_TY) acc[r_off % 11][q] += hv;
            hv = w1 * p0 + w2 * p1 + w3 * p2 + w4 * p3 + w5 * p4;
            {
                const int op = r_off + 1, om = r_off - 1;
                if (op >= 0 && op < LC_TY) acc[op % 11][q] += hv;
                if (om >= 0 && om < LC_TY) acc[om % 11][q] += hv;
            }
            hv = w2 * p0 + w3 * p1 + w4 * p2 + w5 * p3;
            {
                const int op = r_off + 2, om = r_off - 2;
                if (op >= 0 && op < LC_TY) acc[op % 11][q] += hv;
                if (om >= 0 && om < LC_TY) acc[om % 11][q] += hv;
            }
            hv = w3 * p0 + w4 * p1 + w5 * p2;
            {
                const int op = r_off + 3, om = r_off - 3;
                if (op >= 0 && op < LC_TY) acc[op % 11][q] += hv;
                if (om >= 0 && om < LC_TY) acc[om % 11][q] += hv;
            }
            hv = w4 * p0 + w5 * p1;
            {
                const int op = r_off + 4, om = r_off - 4;
                if (op >= 0 && op < LC_TY) acc[op % 11][q] += hv;
                if (om >= 0 && om < LC_TY) acc[om % 11][q] += hv;
            }
            hv = w5 * p0;
            {
                const int op = r_off + 5, om = r_off - 5;
                if (op >= 0 && op < LC_TY) acc[op % 11][q] += hv;
                if (om >= 0 && om < LC_TY) acc[om % 11][q] += hv;
            }
        }

        // output row oc = rr - 10 complete after this source row
        const int oc = rr - 10;
        if (oc >= 0 && oc < LC_TY) {
            const int slot = oc % 11;
            float2 f;
            f.x = acc[slot][0];
            f.y = acc[slot][1];
            *reinterpret_cast<float2*>(dst + (size_t)(r0 + oc) * LC_W + t * 2) = f;
            acc[slot][0] = 0.f;
            acc[slot][1] = 0.f;
        }
    }
#undef LC_WAITB
}

extern "C" void kernel_launch(void* const* d_in, const int* in_sizes, int n_in,
                              void* d_out, int out_size, void* d_ws, size_t ws_size,
                              hipStream_t stream) {
    const float* grid_spikes = (const float*)d_in[0];       // 64*512*512 fp32
    const float* distance_weights = (const float*)d_in[1];  // 5 fp32
    float* out = (float*)d_out;

    dim3 grid(LC_H / LC_TY, 64);  // 32 strips x 64 batches
    dim3 block(LC_NT);
    LocalConnectivity_kernel<<<grid, block, 0, stream>>>(grid_spikes, distance_weights, out);
}